// Round 7
// baseline (216.779 us; speedup 1.0000x reference)
//
#include <hip/hip_runtime.h>
#include <hip/hip_cooperative_groups.h>
#include <math.h>

namespace cg = cooperative_groups;

#define MAXT 2048

__device__ __forceinline__ unsigned keyOf(float f) {
  unsigned b = __float_as_uint(f);
  return b ^ ((b & 0x80000000u) ? 0xFFFFFFFFu : 0x80000000u);
}

__device__ __forceinline__ float waveSum(float v) {
#pragma unroll
  for (int o = 32; o >= 1; o >>= 1) v += __shfl_xor(v, o);
  return v;
}

// Block-wide: find the bin where the cumulative histogram crosses `rank`.
// res[0] = bin, res[1] = remaining rank within that bin (1-indexed).
// Pure function of (h, rank) -> deterministic, recomputed per block.
__device__ __forceinline__ void selectStep(const unsigned* __restrict__ h,
                                           int per, unsigned rank,
                                           unsigned* sc, unsigned* res) {
  int t = threadIdx.x;
  unsigned local[8];
  unsigned s = 0;
  for (int j = 0; j < per; ++j) { local[j] = h[t * per + j]; s += local[j]; }
  sc[t] = s;
  __syncthreads();
  for (int off = 1; off < 256; off <<= 1) {
    unsigned v = (t >= off) ? sc[t - off] : 0u;
    __syncthreads();
    sc[t] += v;
    __syncthreads();
  }
  unsigned incl = sc[t], excl = incl - s;
  if (excl < rank && rank <= incl) {
    unsigned cum = excl;
    for (int j = 0; j < per; ++j) {
      if (cum + local[j] >= rank) {
        res[0] = (unsigned)(t * per + j);
        res[1] = rank - cum;
        break;
      }
      cum += local[j];
    }
  }
  __syncthreads();
}

// One wave per row, both nets. 524 MB read at ~4 TB/s delivered (HBM+L3) --
// measured invariant across 4 structural variants (R1-R6); this is the read
// roofline, so keep the simplest form. No max-subtraction (logits ~N(0,1):
// sum(exp) ~1.6e3, no overflow; abs err ~1e-5 << threshold).
__global__ __launch_bounds__(256) void ce_kernel(
    const float* __restrict__ y1, const float* __restrict__ y2,
    const int* __restrict__ tgt,
    float* __restrict__ l1, float* __restrict__ l2, int N) {
  const float L2E = 1.4426950408889634f;
  const float LN2 = 0.6931471805599453f;
  int wid = threadIdx.x >> 6, lane = threadIdx.x & 63;
  int row = blockIdx.x * 4 + wid;
  if (row >= N) return;
  int t = tgt[row];
  int vecIdx = t >> 2;
  int grp = vecIdx >> 6;      // which of a/b/c/d holds element t (wave-uniform)
  int srcLane = vecIdx & 63;  // wave-uniform
  int comp = t & 3;           // wave-uniform
  const float4* rp1 = (const float4*)(y1 + (size_t)row * 1000);
  const float4* rp2 = (const float4*)(y2 + (size_t)row * 1000);
  float4 a1 = rp1[lane];
  float4 b1 = rp1[lane + 64];
  float4 c1 = rp1[lane + 128];
  float4 a2 = rp2[lane];
  float4 b2 = rp2[lane + 64];
  float4 c2 = rp2[lane + 128];
  float4 d1 = make_float4(-INFINITY, -INFINITY, -INFINITY, -INFINITY);
  float4 d2 = d1;
  if (lane < 58) {  // lane + 192 < 250
    d1 = rp1[lane + 192];
    d2 = rp2[lane + 192];
  }
  float4 sel1 = (grp == 0) ? a1 : (grp == 1) ? b1 : (grp == 2) ? c1 : d1;
  float4 sel2 = (grp == 0) ? a2 : (grp == 1) ? b2 : (grp == 2) ? c2 : d2;
  float cand1 = (comp == 0) ? sel1.x : (comp == 1) ? sel1.y
              : (comp == 2) ? sel1.z : sel1.w;
  float cand2 = (comp == 0) ? sel2.x : (comp == 1) ? sel2.y
              : (comp == 2) ? sel2.z : sel2.w;
  float xt1 = __shfl(cand1, srcLane);
  float xt2 = __shfl(cand2, srcLane);
#define E_(v) exp2f((v) * L2E)
  float s1 = (((E_(a1.x) + E_(a1.y)) + (E_(a1.z) + E_(a1.w))) +
              ((E_(b1.x) + E_(b1.y)) + (E_(b1.z) + E_(b1.w)))) +
             (((E_(c1.x) + E_(c1.y)) + (E_(c1.z) + E_(c1.w))) +
              ((E_(d1.x) + E_(d1.y)) + (E_(d1.z) + E_(d1.w))));
  float s2 = (((E_(a2.x) + E_(a2.y)) + (E_(a2.z) + E_(a2.w))) +
              ((E_(b2.x) + E_(b2.y)) + (E_(b2.z) + E_(b2.w)))) +
             (((E_(c2.x) + E_(c2.y)) + (E_(c2.z) + E_(c2.w))) +
              ((E_(d2.x) + E_(d2.y)) + (E_(d2.z) + E_(d2.w))));
#undef E_
#pragma unroll
  for (int o = 32; o >= 1; o >>= 1) {
    s1 += __shfl_xor(s1, o);
    s2 += __shfl_xor(s2, o);
  }
  if (lane == 0) {
    l1[row] = log2f(s1) * LN2 - xt1;
    l2[row] = log2f(s2) * LN2 - xt2;
  }
}

// Entire selection tail in ONE cooperative kernel (256 blocks x 256).
// Phases separated by grid.sync():
//   0: zero hists + tie counters
//   1: pass-A histogram (top 11 key bits), LDS-privatized
//   2: scanA (redundant per block) + pass-B histogram (key bits 20..10)
//   3: scanB + partial sums + candidate collection
//   4: block 0: final reduction + stable tie resolution + output
__global__ __launch_bounds__(256) void tail_kernel(
    const float* __restrict__ l1, const float* __restrict__ l2,
    unsigned* __restrict__ hA1, unsigned* __restrict__ hA2,
    unsigned* __restrict__ hB1, unsigned* __restrict__ hB2,
    unsigned* __restrict__ tc,
    int* __restrict__ tIdx1, unsigned* __restrict__ tKey1,
    float* __restrict__ tVal1,
    int* __restrict__ tIdx2, unsigned* __restrict__ tKey2,
    float* __restrict__ tVal2,
    float* __restrict__ partials, const int* __restrict__ numKeep,
    float* __restrict__ out, int N) {
  cg::grid_group grid = cg::this_grid();
  int t = threadIdx.x;
  int gid = blockIdx.x * 256 + t;
  int gsize = gridDim.x * 256;

  // ---- phase 0: zero (hA1,hA2,hB1,hB2,tc are contiguous in ws) ----
  for (int j = gid; j < 4 * 2048 + 2; j += gsize) hA1[j] = 0u;
  grid.sync();

  // ---- phase 1: histA, LDS-privatized (keys concentrate in few bins) ----
  __shared__ unsigned lh[2][2048];
  for (int j = t; j < 2048; j += 256) { lh[0][j] = 0u; lh[1][j] = 0u; }
  __syncthreads();
  for (int i = gid; i < N; i += gsize) {
    atomicAdd(&lh[0][keyOf(l1[i]) >> 21], 1u);
    atomicAdd(&lh[1][keyOf(l2[i]) >> 21], 1u);
  }
  __syncthreads();
  for (int j = t; j < 2048; j += 256) {
    unsigned v0 = lh[0][j], v1 = lh[1][j];
    if (v0) atomicAdd(&hA1[j], v0);
    if (v1) atomicAdd(&hA2[j], v1);
  }
  grid.sync();

  // ---- phase 2: scanA + histB (mantissa bits -> well-spread atomics) ----
  __shared__ unsigned sc[256];
  __shared__ unsigned rA1[2], rA2[2], rB1[2], rB2[2];
  unsigned k0 = (unsigned)(*numKeep);
  selectStep(hA1, 8, k0, sc, rA1);
  selectStep(hA2, 8, k0, sc, rA2);
  for (int i = gid; i < N; i += gsize) {
    unsigned k1 = keyOf(l1[i]);
    if ((k1 >> 21) == rA1[0]) atomicAdd(&hB1[(k1 >> 10) & 2047u], 1u);
    unsigned k2 = keyOf(l2[i]);
    if ((k2 >> 21) == rA2[0]) atomicAdd(&hB2[(k2 >> 10) & 2047u], 1u);
  }
  grid.sync();

  // ---- phase 3: scanB + partial sums + candidate collection ----
  selectStep(hB1, 8, rA1[1], sc, rB1);
  selectStep(hB2, 8, rA2[1], sc, rB2);
  unsigned P1 = (rA1[0] << 11) | rB1[0];  // 22-bit prefix (key >> 10)
  unsigned P2 = (rA2[0] << 11) | rB2[0];
  float s0 = 0.f, s1 = 0.f, s2 = 0.f, s3 = 0.f;
  for (int i = gid; i < N; i += gsize) {
    float f1 = l1[i], f2 = l2[i];
    unsigned k1 = keyOf(f1), k2 = keyOf(f2);
    unsigned q1 = k1 >> 10, q2 = k2 >> 10;
    if (q2 < P2) {
      s0 += f1;  // loss_1_update: loss_1 on net-2's selected set
    } else if (q2 == P2) {
      unsigned p = atomicAdd(&tc[1], 1u);
      if (p < MAXT) { tIdx2[p] = i; tKey2[p] = k2; tVal2[p] = f1; }
    }
    if (q1 < P1) {
      s1 += f2;  // loss_2_update: loss_2 on net-1's selected set
    } else if (q1 == P1) {
      unsigned p = atomicAdd(&tc[0], 1u);
      if (p < MAXT) { tIdx1[p] = i; tKey1[p] = k1; tVal1[p] = f2; }
    }
    s2 += f1;
    s3 += f2;
  }
  s0 = waveSum(s0); s1 = waveSum(s1); s2 = waveSum(s2); s3 = waveSum(s3);
  __shared__ float red[4][4];
  int wid = t >> 6, lane = t & 63;
  if (lane == 0) {
    red[wid][0] = s0; red[wid][1] = s1; red[wid][2] = s2; red[wid][3] = s3;
  }
  __syncthreads();
  if (t == 0) {
    for (int q = 0; q < 4; ++q)
      partials[blockIdx.x * 4 + q] =
          red[0][q] + red[1][q] + red[2][q] + red[3][q];
  }
  grid.sync();

  // ---- phase 4: block 0 final reduction + stable tie resolution ----
  if (blockIdx.x != 0) return;
  float u0 = 0.f, u1 = 0.f, u2 = 0.f, u3 = 0.f;
  for (int j = t; j < (int)gridDim.x; j += 256) {
    u0 += partials[j * 4 + 0];
    u1 += partials[j * 4 + 1];
    u2 += partials[j * 4 + 2];
    u3 += partials[j * 4 + 3];
  }
  u0 = waveSum(u0); u1 = waveSum(u1); u2 = waveSum(u2); u3 = waveSum(u3);
  __syncthreads();
  if (lane == 0) {
    red[wid][0] = u0; red[wid][1] = u1; red[wid][2] = u2; red[wid][3] = u3;
  }
  // stable-argsort tie semantics: among equal keys the smallest indices are
  // selected; rank each candidate by (key, idx), keep ranks < need.
  __shared__ float slots[MAXT];
  __shared__ float tieSum[2];
  unsigned needArr[2] = {rB1[1], rB2[1]};
  for (int a = 0; a < 2; ++a) {
    const int* ti = a ? tIdx2 : tIdx1;
    const unsigned* tk = a ? tKey2 : tKey1;
    const float* tv = a ? tVal2 : tVal1;
    int T = min((int)tc[a], MAXT);
    int need = min((int)needArr[a], T);
    __syncthreads();
    for (int j = t; j < T; j += 256) {
      int idx = ti[j];
      unsigned kj = tk[j];
      int rk = 0;
      for (int m = 0; m < T; ++m) {
        unsigned km = tk[m];
        rk += (km < kj || (km == kj && ti[m] < idx)) ? 1 : 0;
      }
      if (rk < need) slots[rk] = tv[j];
    }
    __syncthreads();
    if (t == 0) {
      float s = 0.f;
      for (int j = 0; j < need; ++j) s += slots[j];
      tieSum[a] = s;
    }
  }
  __syncthreads();
  if (t == 0) {
    float a0 = red[0][0] + red[1][0] + red[2][0] + red[3][0] + tieSum[1];
    float a1 = red[0][1] + red[1][1] + red[2][1] + red[3][1] + tieSum[0];
    float a2 = red[0][2] + red[1][2] + red[2][2] + red[3][2];
    float a3 = red[0][3] + red[1][3] + red[2][3] + red[3][3];
    float k = (float)k0;
    out[0] = a0 / k;
    out[1] = a1 / k;
    out[2] = a2 / (float)N;
    out[3] = a3 / (float)N;
  }
}

extern "C" void kernel_launch(void* const* d_in, const int* in_sizes, int n_in,
                              void* d_out, int out_size, void* d_ws,
                              size_t ws_size, hipStream_t stream) {
  const float* y1 = (const float*)d_in[0];
  const float* y2 = (const float*)d_in[1];
  const int* tgt = (const int*)d_in[2];
  const int* numKeep = (const int*)d_in[3];
  int N = in_sizes[2];  // 65536 (C = 1000 hardcoded in ce_kernel)
  float* out = (float*)d_out;

  // workspace layout (hA1..tc contiguous: zeroed as one range in phase 0)
  float* l1 = (float*)d_ws;                // N fp32
  float* l2 = l1 + N;                      // N fp32
  unsigned* hA1 = (unsigned*)(l2 + N);     // 2048
  unsigned* hA2 = hA1 + 2048;              // 2048
  unsigned* hB1 = hA2 + 2048;              // 2048
  unsigned* hB2 = hB1 + 2048;              // 2048
  unsigned* tc = hB2 + 2048;               // 2
  int* tIdx1 = (int*)(tc + 2);             // MAXT
  unsigned* tKey1 = (unsigned*)(tIdx1 + MAXT);
  float* tVal1 = (float*)(tKey1 + MAXT);
  int* tIdx2 = (int*)(tVal1 + MAXT);
  unsigned* tKey2 = (unsigned*)(tIdx2 + MAXT);
  float* tVal2 = (float*)(tKey2 + MAXT);
  float* partials = (float*)(tVal2 + MAXT);  // 256*4

  ce_kernel<<<(N + 3) / 4, 256, 0, stream>>>(y1, y2, tgt, l1, l2, N);

  void* args[] = {(void*)&l1,    (void*)&l2,    (void*)&hA1,  (void*)&hA2,
                  (void*)&hB1,   (void*)&hB2,   (void*)&tc,   (void*)&tIdx1,
                  (void*)&tKey1, (void*)&tVal1, (void*)&tIdx2, (void*)&tKey2,
                  (void*)&tVal2, (void*)&partials, (void*)&numKeep,
                  (void*)&out,   (void*)&N};
  hipLaunchCooperativeKernel((const void*)tail_kernel, dim3(256), dim3(256),
                             args, 0, stream);
}

// Round 8
// 152.848 us; speedup vs baseline: 1.4183x; 1.4183x over previous
//
#include <hip/hip_runtime.h>
#include <math.h>

#define MAXT 2048

__device__ __forceinline__ unsigned keyOf(float f) {
  unsigned b = __float_as_uint(f);
  return b ^ ((b & 0x80000000u) ? 0xFFFFFFFFu : 0x80000000u);
}

__device__ __forceinline__ float waveSum(float v) {
#pragma unroll
  for (int o = 32; o >= 1; o >>= 1) v += __shfl_xor(v, o);
  return v;
}

// Block-wide: find the bin where the cumulative histogram crosses `rank`.
// res[0] = bin, res[1] = remaining rank within that bin (1-indexed).
// Pure function of (h, rank) -> deterministic, recomputed per block.
__device__ __forceinline__ void selectStep(const unsigned* __restrict__ h,
                                           int per, unsigned rank,
                                           unsigned* sc, unsigned* res) {
  int t = threadIdx.x;
  unsigned local[8];
  unsigned s = 0;
  for (int j = 0; j < per; ++j) { local[j] = h[t * per + j]; s += local[j]; }
  sc[t] = s;
  __syncthreads();
  for (int off = 1; off < 256; off <<= 1) {
    unsigned v = (t >= off) ? sc[t - off] : 0u;
    __syncthreads();
    sc[t] += v;
    __syncthreads();
  }
  unsigned incl = sc[t], excl = incl - s;
  if (excl < rank && rank <= incl) {
    unsigned cum = excl;
    for (int j = 0; j < per; ++j) {
      if (cum + local[j] >= rank) {
        res[0] = (unsigned)(t * per + j);
        res[1] = rank - cum;
        break;
      }
      cum += local[j];
    }
  }
  __syncthreads();
}

// Zero histograms + tie/done counters (contiguous region).
__global__ __launch_bounds__(256) void init_kernel(unsigned* __restrict__ z,
                                                   int count) {
  for (int j = threadIdx.x; j < count; j += 256) z[j] = 0u;
}

// EXACT R2-measured ce engine (fastest in-graph of 5 structural variants):
// one wave per row, nets processed sequentially (one 4-float4 burst in
// flight), max-subtracted softmax, y[row,t] extracted from registers via
// one shuffle. 20 VGPR. Do not "optimize" -- concurrent-net loads, asm MLP
// barriers, and persistent waves all measured 6-13 us slower in-graph.
__global__ __launch_bounds__(256) void ce_kernel(
    const float* __restrict__ y1, const float* __restrict__ y2,
    const int* __restrict__ tgt,
    float* __restrict__ l1, float* __restrict__ l2, int N) {
  const float L2E = 1.4426950408889634f;
  const float LN2 = 0.6931471805599453f;
  int wid = threadIdx.x >> 6, lane = threadIdx.x & 63;
  int row = blockIdx.x * 4 + wid;
  if (row >= N) return;
  int t = tgt[row];
  int vecIdx = t >> 2;
  int grp = vecIdx >> 6;      // which of a/b/c/d holds element t (wave-uniform)
  int srcLane = vecIdx & 63;  // wave-uniform
  int comp = t & 3;           // wave-uniform
#pragma unroll
  for (int which = 0; which < 2; ++which) {
    const float* y = which ? y2 : y1;
    const float4* rp = (const float4*)(y + (size_t)row * 1000);
    float4 a = rp[lane];
    float4 b = rp[lane + 64];
    float4 c = rp[lane + 128];
    float4 d = make_float4(-INFINITY, -INFINITY, -INFINITY, -INFINITY);
    if (lane + 192 < 250) d = rp[lane + 192];
    float4 sel = (grp == 0) ? a : (grp == 1) ? b : (grp == 2) ? c : d;
    float cand = (comp == 0) ? sel.x : (comp == 1) ? sel.y
               : (comp == 2) ? sel.z : sel.w;
    float xt = __shfl(cand, srcLane);
    float m = fmaxf(fmaxf(fmaxf(a.x, a.y), fmaxf(a.z, a.w)),
                    fmaxf(fmaxf(b.x, b.y), fmaxf(b.z, b.w)));
    m = fmaxf(m, fmaxf(fmaxf(c.x, c.y), fmaxf(c.z, c.w)));
    m = fmaxf(m, fmaxf(fmaxf(d.x, d.y), fmaxf(d.z, d.w)));
#pragma unroll
    for (int o = 32; o >= 1; o >>= 1) m = fmaxf(m, __shfl_xor(m, o));
    float s = exp2f((a.x - m) * L2E) + exp2f((a.y - m) * L2E) +
              exp2f((a.z - m) * L2E) + exp2f((a.w - m) * L2E) +
              exp2f((b.x - m) * L2E) + exp2f((b.y - m) * L2E) +
              exp2f((b.z - m) * L2E) + exp2f((b.w - m) * L2E) +
              exp2f((c.x - m) * L2E) + exp2f((c.y - m) * L2E) +
              exp2f((c.z - m) * L2E) + exp2f((c.w - m) * L2E) +
              exp2f((d.x - m) * L2E) + exp2f((d.y - m) * L2E) +
              exp2f((d.z - m) * L2E) + exp2f((d.w - m) * L2E);
    s = waveSum(s);
    if (lane == 0) {
      float loss = log2f(s) * LN2 + m - xt;
      (which ? l2 : l1)[row] = loss;
    }
  }
}

// Pass-A histogram (top 11 key bits), LDS-privatized (keys concentrate in a
// handful of top-bit bins; global per-element atomics would serialize).
__global__ __launch_bounds__(256) void histA_kernel(
    const float* __restrict__ l1, const float* __restrict__ l2,
    unsigned* __restrict__ hA1, unsigned* __restrict__ hA2, int N) {
  __shared__ unsigned lh[2][2048];
  int t = threadIdx.x;
  for (int j = t; j < 2048; j += 256) { lh[0][j] = 0u; lh[1][j] = 0u; }
  __syncthreads();
  for (int i = blockIdx.x * blockDim.x + t; i < N;
       i += gridDim.x * blockDim.x) {
    atomicAdd(&lh[0][keyOf(l1[i]) >> 21], 1u);
    atomicAdd(&lh[1][keyOf(l2[i]) >> 21], 1u);
  }
  __syncthreads();
  for (int j = t; j < 2048; j += 256) {
    unsigned v0 = lh[0][j], v1 = lh[1][j];
    if (v0) atomicAdd(&hA1[j], v0);
    if (v1) atomicAdd(&hA2[j], v1);
  }
}

// Pass B: redundant pass-A scan per block, then histogram key bits 20..10 of
// elements in the selected A-bin (mantissa bits -> well-spread atomics).
__global__ __launch_bounds__(256) void histB_kernel(
    const float* __restrict__ l1, const float* __restrict__ l2,
    const unsigned* __restrict__ hA1, const unsigned* __restrict__ hA2,
    unsigned* __restrict__ hB1, unsigned* __restrict__ hB2,
    const int* __restrict__ numKeep, int N) {
  __shared__ unsigned sc[256];
  __shared__ unsigned resA1[2], resA2[2];
  unsigned k0 = (unsigned)(*numKeep);
  selectStep(hA1, 8, k0, sc, resA1);
  selectStep(hA2, 8, k0, sc, resA2);
  unsigned a1 = resA1[0], a2 = resA2[0];
  for (int i = blockIdx.x * blockDim.x + threadIdx.x; i < N;
       i += gridDim.x * blockDim.x) {
    unsigned k1 = keyOf(l1[i]);
    if ((k1 >> 21) == a1) atomicAdd(&hB1[(k1 >> 10) & 2047u], 1u);
    unsigned k2 = keyOf(l2[i]);
    if ((k2 >> 21) == a2) atomicAdd(&hB2[(k2 >> 10) & 2047u], 1u);
  }
}

// Partial sums + candidate collection + (last block) final reduction.
// The 22-bit prefix (scans A,B) isolates ~tens of candidates; elements with
// strictly-smaller prefix are summed directly, prefix-matching ones are
// collected (idx, key, other-net loss) and rank-resolved by (key, idx) --
// exactly stable-argsort tie semantics.
__global__ __launch_bounds__(256) void partial_kernel(
    const float* __restrict__ l1, const float* __restrict__ l2,
    const unsigned* __restrict__ hA1, const unsigned* __restrict__ hA2,
    const unsigned* __restrict__ hB1, const unsigned* __restrict__ hB2,
    const int* __restrict__ numKeep, unsigned* __restrict__ tc,
    unsigned* __restrict__ done,
    int* __restrict__ tIdx1, unsigned* __restrict__ tKey1, float* __restrict__ tVal1,
    int* __restrict__ tIdx2, unsigned* __restrict__ tKey2, float* __restrict__ tVal2,
    float* __restrict__ partials, float* __restrict__ out, int N) {
  __shared__ unsigned sc[256];
  __shared__ unsigned rA1[2], rA2[2], rB1[2], rB2[2];
  unsigned k0 = (unsigned)(*numKeep);
  selectStep(hA1, 8, k0, sc, rA1);
  selectStep(hA2, 8, k0, sc, rA2);
  selectStep(hB1, 8, rA1[1], sc, rB1);
  selectStep(hB2, 8, rA2[1], sc, rB2);
  unsigned P1 = (rA1[0] << 11) | rB1[0];  // 22-bit prefix (key >> 10)
  unsigned P2 = (rA2[0] << 11) | rB2[0];
  float s0 = 0.f, s1 = 0.f, s2 = 0.f, s3 = 0.f;
  for (int i = blockIdx.x * blockDim.x + threadIdx.x; i < N;
       i += gridDim.x * blockDim.x) {
    float f1 = l1[i], f2 = l2[i];
    unsigned k1 = keyOf(f1), k2 = keyOf(f2);
    unsigned q1 = k1 >> 10, q2 = k2 >> 10;
    if (q2 < P2) {
      s0 += f1;  // loss_1_update: loss_1 on net-2's selected set
    } else if (q2 == P2) {
      unsigned p = atomicAdd(&tc[1], 1u);
      if (p < MAXT) { tIdx2[p] = i; tKey2[p] = k2; tVal2[p] = f1; }
    }
    if (q1 < P1) {
      s1 += f2;  // loss_2_update: loss_2 on net-1's selected set
    } else if (q1 == P1) {
      unsigned p = atomicAdd(&tc[0], 1u);
      if (p < MAXT) { tIdx1[p] = i; tKey1[p] = k1; tVal1[p] = f2; }
    }
    s2 += f1;
    s3 += f2;
  }
  s0 = waveSum(s0); s1 = waveSum(s1); s2 = waveSum(s2); s3 = waveSum(s3);
  __shared__ float red[4][4];
  int wid = threadIdx.x >> 6, lane = threadIdx.x & 63;
  if (lane == 0) {
    red[wid][0] = s0; red[wid][1] = s1; red[wid][2] = s2; red[wid][3] = s3;
  }
  __syncthreads();
  if (threadIdx.x == 0) {
    for (int q = 0; q < 4; ++q)
      partials[blockIdx.x * 4 + q] =
          red[0][q] + red[1][q] + red[2][q] + red[3][q];
  }
  // ---- last-block final reduction ----
  __shared__ unsigned amLast;
  __threadfence();
  if (threadIdx.x == 0)
    amLast = (atomicAdd(done, 1u) == (unsigned)(gridDim.x - 1)) ? 1u : 0u;
  __syncthreads();
  if (!amLast) return;
  __threadfence();
  int t = threadIdx.x;
  float u0 = 0.f, u1 = 0.f, u2 = 0.f, u3 = 0.f;
  for (int j = t; j < (int)gridDim.x; j += 256) {
    u0 += partials[j * 4 + 0];
    u1 += partials[j * 4 + 1];
    u2 += partials[j * 4 + 2];
    u3 += partials[j * 4 + 3];
  }
  u0 = waveSum(u0); u1 = waveSum(u1); u2 = waveSum(u2); u3 = waveSum(u3);
  __syncthreads();
  if (lane == 0) {
    red[wid][0] = u0; red[wid][1] = u1; red[wid][2] = u2; red[wid][3] = u3;
  }
  // candidate rank resolution (stable: order by (key, idx))
  __shared__ float slots[MAXT];
  __shared__ float tieSum[2];
  unsigned needArr[2] = {rB1[1], rB2[1]};
  for (int a = 0; a < 2; ++a) {
    const int* ti = a ? tIdx2 : tIdx1;
    const unsigned* tk = a ? tKey2 : tKey1;
    const float* tv = a ? tVal2 : tVal1;
    int T = min((int)tc[a], MAXT);
    int need = min((int)needArr[a], T);
    __syncthreads();
    for (int j = t; j < T; j += 256) {
      int idx = ti[j];
      unsigned kj = tk[j];
      int rk = 0;
      for (int m = 0; m < T; ++m) {
        unsigned km = tk[m];
        rk += (km < kj || (km == kj && ti[m] < idx)) ? 1 : 0;
      }
      if (rk < need) slots[rk] = tv[j];
    }
    __syncthreads();
    if (t == 0) {
      float s = 0.f;
      for (int j = 0; j < need; ++j) s += slots[j];
      tieSum[a] = s;
    }
  }
  __syncthreads();
  if (t == 0) {
    float a0 = red[0][0] + red[1][0] + red[2][0] + red[3][0] + tieSum[1];
    float a1 = red[0][1] + red[1][1] + red[2][1] + red[3][1] + tieSum[0];
    float a2 = red[0][2] + red[1][2] + red[2][2] + red[3][2];
    float a3 = red[0][3] + red[1][3] + red[2][3] + red[3][3];
    float k = (float)k0;
    out[0] = a0 / k;
    out[1] = a1 / k;
    out[2] = a2 / (float)N;
    out[3] = a3 / (float)N;
  }
}

extern "C" void kernel_launch(void* const* d_in, const int* in_sizes, int n_in,
                              void* d_out, int out_size, void* d_ws,
                              size_t ws_size, hipStream_t stream) {
  const float* y1 = (const float*)d_in[0];
  const float* y2 = (const float*)d_in[1];
  const int* tgt = (const int*)d_in[2];
  const int* numKeep = (const int*)d_in[3];
  int N = in_sizes[2];  // 65536 (C = 1000 hardcoded in ce_kernel)
  float* out = (float*)d_out;

  // workspace layout (hA1..done contiguous: zeroed as one range by init)
  float* l1 = (float*)d_ws;                // N fp32
  float* l2 = l1 + N;                      // N fp32
  unsigned* hA1 = (unsigned*)(l2 + N);     // 2048
  unsigned* hA2 = hA1 + 2048;              // 2048
  unsigned* hB1 = hA2 + 2048;              // 2048
  unsigned* hB2 = hB1 + 2048;              // 2048
  unsigned* tc = hB2 + 2048;               // 2
  unsigned* done = tc + 2;                 // 1
  int* tIdx1 = (int*)(done + 1);           // MAXT
  unsigned* tKey1 = (unsigned*)(tIdx1 + MAXT);
  float* tVal1 = (float*)(tKey1 + MAXT);
  int* tIdx2 = (int*)(tVal1 + MAXT);
  unsigned* tKey2 = (unsigned*)(tIdx2 + MAXT);
  float* tVal2 = (float*)(tKey2 + MAXT);
  float* partials = (float*)(tVal2 + MAXT);  // 256*4

  init_kernel<<<1, 256, 0, stream>>>(hA1, 4 * 2048 + 3);
  ce_kernel<<<(N + 3) / 4, 256, 0, stream>>>(y1, y2, tgt, l1, l2, N);
  histA_kernel<<<256, 256, 0, stream>>>(l1, l2, hA1, hA2, N);
  histB_kernel<<<256, 256, 0, stream>>>(l1, l2, hA1, hA2, hB1, hB2, numKeep, N);
  partial_kernel<<<256, 256, 0, stream>>>(l1, l2, hA1, hA2, hB1, hB2, numKeep,
                                          tc, done, tIdx1, tKey1, tVal1, tIdx2,
                                          tKey2, tVal2, partials, out, N);
}

// Round 10
// 138.186 us; speedup vs baseline: 1.5688x; 1.1061x over previous
//
#include <hip/hip_runtime.h>
#include <math.h>

#define MAXT 2048

typedef float floatx4 __attribute__((ext_vector_type(4)));

__device__ __forceinline__ unsigned keyOf(float f) {
  unsigned b = __float_as_uint(f);
  return b ^ ((b & 0x80000000u) ? 0xFFFFFFFFu : 0x80000000u);
}

__device__ __forceinline__ float waveSum(float v) {
#pragma unroll
  for (int o = 32; o >= 1; o >>= 1) v += __shfl_xor(v, o);
  return v;
}

// Non-temporal float4 load: builtin requires a native vector type, not
// HIP_vector_type (struct) -- go through ext_vector_type(4).
__device__ __forceinline__ float4 ntLoad4(const float4* p) {
  floatx4 v = __builtin_nontemporal_load((const floatx4*)p);
  return make_float4(v.x, v.y, v.z, v.w);
}

// Block-wide: find the bin where the cumulative histogram crosses `rank`.
// res[0] = bin, res[1] = remaining rank within that bin (1-indexed).
// Pure function of (h, rank) -> deterministic, recomputed per block.
__device__ __forceinline__ void selectStep(const unsigned* __restrict__ h,
                                           int per, unsigned rank,
                                           unsigned* sc, unsigned* res) {
  int t = threadIdx.x;
  unsigned local[8];
  unsigned s = 0;
  for (int j = 0; j < per; ++j) { local[j] = h[t * per + j]; s += local[j]; }
  sc[t] = s;
  __syncthreads();
  for (int off = 1; off < 256; off <<= 1) {
    unsigned v = (t >= off) ? sc[t - off] : 0u;
    __syncthreads();
    sc[t] += v;
    __syncthreads();
  }
  unsigned incl = sc[t], excl = incl - s;
  if (excl < rank && rank <= incl) {
    unsigned cum = excl;
    for (int j = 0; j < per; ++j) {
      if (cum + local[j] >= rank) {
        res[0] = (unsigned)(t * per + j);
        res[1] = rank - cum;
        break;
      }
      cum += local[j];
    }
  }
  __syncthreads();
}

// Zero histograms + tie/done counters (contiguous region).
__global__ __launch_bounds__(256) void init_kernel(unsigned* __restrict__ z,
                                                   int count) {
  for (int j = threadIdx.x; j < count; j += 256) z[j] = 0u;
}

// R2 ce engine with ONE change: y1/y2 reads are non-temporal (nt bit).
// The two 256 MB inputs thrash the 256 MB L3 (profiled: exactly half the
// 524 MB footprint HBM-fetched, both halves at ~1.7 TB/s); nt streaming
// avoids L3 allocation so reads can stream like the 7 TB/s fill path.
__global__ __launch_bounds__(256) void ce_kernel(
    const float* __restrict__ y1, const float* __restrict__ y2,
    const int* __restrict__ tgt,
    float* __restrict__ l1, float* __restrict__ l2, int N) {
  const float L2E = 1.4426950408889634f;
  const float LN2 = 0.6931471805599453f;
  int wid = threadIdx.x >> 6, lane = threadIdx.x & 63;
  int row = blockIdx.x * 4 + wid;
  if (row >= N) return;
  int t = tgt[row];
  int vecIdx = t >> 2;
  int grp = vecIdx >> 6;      // which of a/b/c/d holds element t (wave-uniform)
  int srcLane = vecIdx & 63;  // wave-uniform
  int comp = t & 3;           // wave-uniform
#pragma unroll
  for (int which = 0; which < 2; ++which) {
    const float* y = which ? y2 : y1;
    const float4* rp = (const float4*)(y + (size_t)row * 1000);
    float4 a = ntLoad4(rp + lane);
    float4 b = ntLoad4(rp + lane + 64);
    float4 c = ntLoad4(rp + lane + 128);
    float4 d = make_float4(-INFINITY, -INFINITY, -INFINITY, -INFINITY);
    if (lane + 192 < 250) d = ntLoad4(rp + lane + 192);
    float4 sel = (grp == 0) ? a : (grp == 1) ? b : (grp == 2) ? c : d;
    float cand = (comp == 0) ? sel.x : (comp == 1) ? sel.y
               : (comp == 2) ? sel.z : sel.w;
    float xt = __shfl(cand, srcLane);
    float m = fmaxf(fmaxf(fmaxf(a.x, a.y), fmaxf(a.z, a.w)),
                    fmaxf(fmaxf(b.x, b.y), fmaxf(b.z, b.w)));
    m = fmaxf(m, fmaxf(fmaxf(c.x, c.y), fmaxf(c.z, c.w)));
    m = fmaxf(m, fmaxf(fmaxf(d.x, d.y), fmaxf(d.z, d.w)));
#pragma unroll
    for (int o = 32; o >= 1; o >>= 1) m = fmaxf(m, __shfl_xor(m, o));
    float s = exp2f((a.x - m) * L2E) + exp2f((a.y - m) * L2E) +
              exp2f((a.z - m) * L2E) + exp2f((a.w - m) * L2E) +
              exp2f((b.x - m) * L2E) + exp2f((b.y - m) * L2E) +
              exp2f((b.z - m) * L2E) + exp2f((b.w - m) * L2E) +
              exp2f((c.x - m) * L2E) + exp2f((c.y - m) * L2E) +
              exp2f((c.z - m) * L2E) + exp2f((c.w - m) * L2E) +
              exp2f((d.x - m) * L2E) + exp2f((d.y - m) * L2E) +
              exp2f((d.z - m) * L2E) + exp2f((d.w - m) * L2E);
    s = waveSum(s);
    if (lane == 0) {
      float loss = log2f(s) * LN2 + m - xt;
      (which ? l2 : l1)[row] = loss;
    }
  }
}

// Pass-A histogram (top 11 key bits), LDS-privatized (keys concentrate in a
// handful of top-bit bins; global per-element atomics would serialize).
__global__ __launch_bounds__(256) void histA_kernel(
    const float* __restrict__ l1, const float* __restrict__ l2,
    unsigned* __restrict__ hA1, unsigned* __restrict__ hA2, int N) {
  __shared__ unsigned lh[2][2048];
  int t = threadIdx.x;
  for (int j = t; j < 2048; j += 256) { lh[0][j] = 0u; lh[1][j] = 0u; }
  __syncthreads();
  for (int i = blockIdx.x * blockDim.x + t; i < N;
       i += gridDim.x * blockDim.x) {
    atomicAdd(&lh[0][keyOf(l1[i]) >> 21], 1u);
    atomicAdd(&lh[1][keyOf(l2[i]) >> 21], 1u);
  }
  __syncthreads();
  for (int j = t; j < 2048; j += 256) {
    unsigned v0 = lh[0][j], v1 = lh[1][j];
    if (v0) atomicAdd(&hA1[j], v0);
    if (v1) atomicAdd(&hA2[j], v1);
  }
}

// Pass B: redundant pass-A scan per block, then histogram key bits 20..10 of
// elements in the selected A-bin (mantissa bits -> well-spread atomics).
__global__ __launch_bounds__(256) void histB_kernel(
    const float* __restrict__ l1, const float* __restrict__ l2,
    const unsigned* __restrict__ hA1, const unsigned* __restrict__ hA2,
    unsigned* __restrict__ hB1, unsigned* __restrict__ hB2,
    const int* __restrict__ numKeep, int N) {
  __shared__ unsigned sc[256];
  __shared__ unsigned resA1[2], resA2[2];
  unsigned k0 = (unsigned)(*numKeep);
  selectStep(hA1, 8, k0, sc, resA1);
  selectStep(hA2, 8, k0, sc, resA2);
  unsigned a1 = resA1[0], a2 = resA2[0];
  for (int i = blockIdx.x * blockDim.x + threadIdx.x; i < N;
       i += gridDim.x * blockDim.x) {
    unsigned k1 = keyOf(l1[i]);
    if ((k1 >> 21) == a1) atomicAdd(&hB1[(k1 >> 10) & 2047u], 1u);
    unsigned k2 = keyOf(l2[i]);
    if ((k2 >> 21) == a2) atomicAdd(&hB2[(k2 >> 10) & 2047u], 1u);
  }
}

// Partial sums + candidate collection + (last block) final reduction.
// The 22-bit prefix (scans A,B) isolates ~tens of candidates; elements with
// strictly-smaller prefix are summed directly, prefix-matching ones are
// collected (idx, key, other-net loss) and rank-resolved by (key, idx) --
// exactly stable-argsort tie semantics.
__global__ __launch_bounds__(256) void partial_kernel(
    const float* __restrict__ l1, const float* __restrict__ l2,
    const unsigned* __restrict__ hA1, const unsigned* __restrict__ hA2,
    const unsigned* __restrict__ hB1, const unsigned* __restrict__ hB2,
    const int* __restrict__ numKeep, unsigned* __restrict__ tc,
    unsigned* __restrict__ done,
    int* __restrict__ tIdx1, unsigned* __restrict__ tKey1, float* __restrict__ tVal1,
    int* __restrict__ tIdx2, unsigned* __restrict__ tKey2, float* __restrict__ tVal2,
    float* __restrict__ partials, float* __restrict__ out, int N) {
  __shared__ unsigned sc[256];
  __shared__ unsigned rA1[2], rA2[2], rB1[2], rB2[2];
  unsigned k0 = (unsigned)(*numKeep);
  selectStep(hA1, 8, k0, sc, rA1);
  selectStep(hA2, 8, k0, sc, rA2);
  selectStep(hB1, 8, rA1[1], sc, rB1);
  selectStep(hB2, 8, rA2[1], sc, rB2);
  unsigned P1 = (rA1[0] << 11) | rB1[0];  // 22-bit prefix (key >> 10)
  unsigned P2 = (rA2[0] << 11) | rB2[0];
  float s0 = 0.f, s1 = 0.f, s2 = 0.f, s3 = 0.f;
  for (int i = blockIdx.x * blockDim.x + threadIdx.x; i < N;
       i += gridDim.x * blockDim.x) {
    float f1 = l1[i], f2 = l2[i];
    unsigned k1 = keyOf(f1), k2 = keyOf(f2);
    unsigned q1 = k1 >> 10, q2 = k2 >> 10;
    if (q2 < P2) {
      s0 += f1;  // loss_1_update: loss_1 on net-2's selected set
    } else if (q2 == P2) {
      unsigned p = atomicAdd(&tc[1], 1u);
      if (p < MAXT) { tIdx2[p] = i; tKey2[p] = k2; tVal2[p] = f1; }
    }
    if (q1 < P1) {
      s1 += f2;  // loss_2_update: loss_2 on net-1's selected set
    } else if (q1 == P1) {
      unsigned p = atomicAdd(&tc[0], 1u);
      if (p < MAXT) { tIdx1[p] = i; tKey1[p] = k1; tVal1[p] = f2; }
    }
    s2 += f1;
    s3 += f2;
  }
  s0 = waveSum(s0); s1 = waveSum(s1); s2 = waveSum(s2); s3 = waveSum(s3);
  __shared__ float red[4][4];
  int wid = threadIdx.x >> 6, lane = threadIdx.x & 63;
  if (lane == 0) {
    red[wid][0] = s0; red[wid][1] = s1; red[wid][2] = s2; red[wid][3] = s3;
  }
  __syncthreads();
  if (threadIdx.x == 0) {
    for (int q = 0; q < 4; ++q)
      partials[blockIdx.x * 4 + q] =
          red[0][q] + red[1][q] + red[2][q] + red[3][q];
  }
  // ---- last-block final reduction ----
  __shared__ unsigned amLast;
  __threadfence();
  if (threadIdx.x == 0)
    amLast = (atomicAdd(done, 1u) == (unsigned)(gridDim.x - 1)) ? 1u : 0u;
  __syncthreads();
  if (!amLast) return;
  __threadfence();
  int t = threadIdx.x;
  float u0 = 0.f, u1 = 0.f, u2 = 0.f, u3 = 0.f;
  for (int j = t; j < (int)gridDim.x; j += 256) {
    u0 += partials[j * 4 + 0];
    u1 += partials[j * 4 + 1];
    u2 += partials[j * 4 + 2];
    u3 += partials[j * 4 + 3];
  }
  u0 = waveSum(u0); u1 = waveSum(u1); u2 = waveSum(u2); u3 = waveSum(u3);
  __syncthreads();
  if (lane == 0) {
    red[wid][0] = u0; red[wid][1] = u1; red[wid][2] = u2; red[wid][3] = u3;
  }
  // candidate rank resolution (stable: order by (key, idx))
  __shared__ float slots[MAXT];
  __shared__ float tieSum[2];
  unsigned needArr[2] = {rB1[1], rB2[1]};
  for (int a = 0; a < 2; ++a) {
    const int* ti = a ? tIdx2 : tIdx1;
    const unsigned* tk = a ? tKey2 : tKey1;
    const float* tv = a ? tVal2 : tVal1;
    int T = min((int)tc[a], MAXT);
    int need = min((int)needArr[a], T);
    __syncthreads();
    for (int j = t; j < T; j += 256) {
      int idx = ti[j];
      unsigned kj = tk[j];
      int rk = 0;
      for (int m = 0; m < T; ++m) {
        unsigned km = tk[m];
        rk += (km < kj || (km == kj && ti[m] < idx)) ? 1 : 0;
      }
      if (rk < need) slots[rk] = tv[j];
    }
    __syncthreads();
    if (t == 0) {
      float s = 0.f;
      for (int j = 0; j < need; ++j) s += slots[j];
      tieSum[a] = s;
    }
  }
  __syncthreads();
  if (t == 0) {
    float a0 = red[0][0] + red[1][0] + red[2][0] + red[3][0] + tieSum[1];
    float a1 = red[0][1] + red[1][1] + red[2][1] + red[3][1] + tieSum[0];
    float a2 = red[0][2] + red[1][2] + red[2][2] + red[3][2];
    float a3 = red[0][3] + red[1][3] + red[2][3] + red[3][3];
    float k = (float)k0;
    out[0] = a0 / k;
    out[1] = a1 / k;
    out[2] = a2 / (float)N;
    out[3] = a3 / (float)N;
  }
}

extern "C" void kernel_launch(void* const* d_in, const int* in_sizes, int n_in,
                              void* d_out, int out_size, void* d_ws,
                              size_t ws_size, hipStream_t stream) {
  const float* y1 = (const float*)d_in[0];
  const float* y2 = (const float*)d_in[1];
  const int* tgt = (const int*)d_in[2];
  const int* numKeep = (const int*)d_in[3];
  int N = in_sizes[2];  // 65536 (C = 1000 hardcoded in ce_kernel)
  float* out = (float*)d_out;

  // workspace layout (hA1..done contiguous: zeroed as one range by init)
  float* l1 = (float*)d_ws;                // N fp32
  float* l2 = l1 + N;                      // N fp32
  unsigned* hA1 = (unsigned*)(l2 + N);     // 2048
  unsigned* hA2 = hA1 + 2048;              // 2048
  unsigned* hB1 = hA2 + 2048;              // 2048
  unsigned* hB2 = hB1 + 2048;              // 2048
  unsigned* tc = hB2 + 2048;               // 2
  unsigned* done = tc + 2;                 // 1
  int* tIdx1 = (int*)(done + 1);           // MAXT
  unsigned* tKey1 = (unsigned*)(tIdx1 + MAXT);
  float* tVal1 = (float*)(tKey1 + MAXT);
  int* tIdx2 = (int*)(tVal1 + MAXT);
  unsigned* tKey2 = (unsigned*)(tIdx2 + MAXT);
  float* tVal2 = (float*)(tKey2 + MAXT);
  float* partials = (float*)(tVal2 + MAXT);  // 256*4

  init_kernel<<<1, 256, 0, stream>>>(hA1, 4 * 2048 + 3);
  ce_kernel<<<(N + 3) / 4, 256, 0, stream>>>(y1, y2, tgt, l1, l2, N);
  histA_kernel<<<256, 256, 0, stream>>>(l1, l2, hA1, hA2, N);
  histB_kernel<<<256, 256, 0, stream>>>(l1, l2, hA1, hA2, hB1, hB2, numKeep, N);
  partial_kernel<<<256, 256, 0, stream>>>(l1, l2, hA1, hA2, hB1, hB2, numKeep,
                                          tc, done, tIdx1, tKey1, tVal1, tIdx2,
                                          tKey2, tVal2, partials, out, N);
}